// Round 1
// baseline (527.827 us; speedup 1.0000x reference)
//
#include <hip/hip_runtime.h>
#include <hip/hip_bf16.h>

typedef __attribute__((ext_vector_type(8))) short short8;
typedef __attribute__((ext_vector_type(4))) float f32x4;

#define B_   4
#define S_   2048
#define D_   1024
#define H_   16
#define HD_  64
#define M_   (B_ * S_)      // 8192
#define N3_  (3 * D_)       // 3072

// ---------------------------------------------------------------- casts ----
__global__ __launch_bounds__(256) void cast_f32_bf16(
    const float* __restrict__ in, __hip_bfloat16* __restrict__ out, int n) {
  int i = (blockIdx.x * 256 + threadIdx.x) * 4;
  if (i + 3 < n) {
    float4 v = *(const float4*)(in + i);
    union { ushort4 u4; __hip_bfloat16 h[4]; } p;
    p.h[0] = __float2bfloat16(v.x);
    p.h[1] = __float2bfloat16(v.y);
    p.h[2] = __float2bfloat16(v.z);
    p.h[3] = __float2bfloat16(v.w);
    *(ushort4*)(out + i) = p.u4;
  }
}

// in: [rows][cols] fp32 -> out: [cols][rows] bf16
__global__ __launch_bounds__(256) void transpose_cast(
    const float* __restrict__ in, __hip_bfloat16* __restrict__ out,
    int rows, int cols) {
  __shared__ float tile[32][33];
  int bx = blockIdx.x * 32;  // col base
  int by = blockIdx.y * 32;  // row base
  int tx = threadIdx.x, ty = threadIdx.y;   // (32, 8)
#pragma unroll
  for (int i = 0; i < 4; ++i)
    tile[ty + i * 8][tx] = in[(size_t)(by + ty + i * 8) * cols + bx + tx];
  __syncthreads();
#pragma unroll
  for (int i = 0; i < 4; ++i)
    out[(size_t)(bx + ty + i * 8) * rows + by + tx] =
        __float2bfloat16(tile[tx][ty + i * 8]);
}

// ----------------------------------------------------------------- GEMM ----
// C[M][N] = A[M][K] * Bt[N][K]^T + bias[N].  128x128 tile, BK=32, 256 thr.
__device__ inline void store_out(float* p, float v) { *p = v; }
__device__ inline void store_out(__hip_bfloat16* p, float v) {
  *p = __float2bfloat16(v);
}

template <typename OUT_T>
__global__ __launch_bounds__(256) void gemm_bt_bias(
    const __hip_bfloat16* __restrict__ A, const __hip_bfloat16* __restrict__ Bt,
    const float* __restrict__ bias, OUT_T* __restrict__ C,
    int M, int N, int K) {
  __shared__ __hip_bfloat16 Alds[128][40];  // stride 40 elems = 80 B (16B-mult)
  __shared__ __hip_bfloat16 Blds[128][40];
  const int t = threadIdx.x;
  const int wave = t >> 6, lane = t & 63;
  const int quad = lane >> 4, l15 = lane & 15;
  const int wm = (wave >> 1) * 64, wn = (wave & 1) * 64;
  const int m0 = blockIdx.y * 128, n0 = blockIdx.x * 128;

  f32x4 acc[4][4] = {};

  for (int k0 = 0; k0 < K; k0 += 32) {
#pragma unroll
    for (int i = 0; i < 2; ++i) {             // 512 16B chunks per operand
      int c = t + 256 * i;
      int row = c >> 2, seg = c & 3;
      *(uint4*)(&Alds[row][seg * 8]) =
          *(const uint4*)(A + (size_t)(m0 + row) * K + k0 + seg * 8);
      *(uint4*)(&Blds[row][seg * 8]) =
          *(const uint4*)(Bt + (size_t)(n0 + row) * K + k0 + seg * 8);
    }
    __syncthreads();
    short8 a[4], b[4];
#pragma unroll
    for (int mt = 0; mt < 4; ++mt)
      a[mt] = *(const short8*)(&Alds[wm + mt * 16 + l15][quad * 8]);
#pragma unroll
    for (int nt = 0; nt < 4; ++nt)
      b[nt] = *(const short8*)(&Blds[wn + nt * 16 + l15][quad * 8]);
#pragma unroll
    for (int mt = 0; mt < 4; ++mt)
#pragma unroll
      for (int nt = 0; nt < 4; ++nt)
        acc[mt][nt] = __builtin_amdgcn_mfma_f32_16x16x32_bf16(
            a[mt], b[nt], acc[mt][nt], 0, 0, 0);
    __syncthreads();
  }

#pragma unroll
  for (int mt = 0; mt < 4; ++mt)
#pragma unroll
    for (int nt = 0; nt < 4; ++nt) {
      int col = n0 + wn + nt * 16 + l15;
      float bv = bias[col];
#pragma unroll
      for (int r = 0; r < 4; ++r) {
        int row = m0 + wm + mt * 16 + quad * 4 + r;
        store_out(C + (size_t)row * N + col, acc[mt][nt][r] + bv);
      }
    }
}

// ------------------------------------------------------ flash attention ----
// qkv: [B*S][3072] bf16, col = group*1024 + h*64 + d.  ctx: [B*S][1024] bf16.
// Block = (qb, h, b): 64 q-rows, 4 waves x 16 rows, online softmax.
__global__ __launch_bounds__(256) void attn_causal(
    const __hip_bfloat16* __restrict__ qkv, __hip_bfloat16* __restrict__ ctx) {
  __shared__ __hip_bfloat16 Klds[64][72];      // [kpos][d], pad to 72
  __shared__ __hip_bfloat16 Vlds[64][72];      // [d][kpos] (transposed)
  __shared__ __hip_bfloat16 Plds[4][16][72];   // per-wave P round-trip

  const int t = threadIdx.x;
  const int wave = t >> 6, lane = t & 63;
  const int quad = lane >> 4, l15 = lane & 15;
  const int qb = blockIdx.x, h = blockIdx.y, b = blockIdx.z;

  const size_t base = (size_t)b * S_ * N3_ + h * HD_;

  // Q fragments (A-layout), kept in registers for whole block
  const int qrow = qb * 64 + wave * 16 + l15;
  short8 qf0 = *(const short8*)(qkv + base + (size_t)qrow * N3_ + quad * 8);
  short8 qf1 = *(const short8*)(qkv + base + (size_t)qrow * N3_ + 32 + quad * 8);

  f32x4 o[4] = {};
  float m_r[4], l_r[4];
#pragma unroll
  for (int r = 0; r < 4; ++r) { m_r[r] = -1e30f; l_r[r] = 0.f; }

  const int nkb = qb + 1;
  for (int kb = 0; kb < nkb; ++kb) {
    // ---- stage K [64][64] natural, V [64][64] transposed ----
#pragma unroll
    for (int i = 0; i < 2; ++i) {
      int c = t + 256 * i;
      int row = c >> 3, seg = c & 7;
      *(uint4*)(&Klds[row][seg * 8]) = *(const uint4*)(
          qkv + base + D_ + (size_t)(kb * 64 + row) * N3_ + seg * 8);
      short8 vv = *(const short8*)(
          qkv + base + 2 * D_ + (size_t)(kb * 64 + row) * N3_ + seg * 8);
#pragma unroll
      for (int j = 0; j < 8; ++j)
        Vlds[seg * 8 + j][row] = ((const __hip_bfloat16*)&vv)[j];
    }
    __syncthreads();

    // ---- scores: S = Q K^T * scale ----
    f32x4 s[4];
#pragma unroll
    for (int nt = 0; nt < 4; ++nt) {
      f32x4 z = {};
      short8 k0 = *(const short8*)(&Klds[nt * 16 + l15][quad * 8]);
      short8 k1 = *(const short8*)(&Klds[nt * 16 + l15][32 + quad * 8]);
      z = __builtin_amdgcn_mfma_f32_16x16x32_bf16(qf0, k0, z, 0, 0, 0);
      z = __builtin_amdgcn_mfma_f32_16x16x32_bf16(qf1, k1, z, 0, 0, 0);
      s[nt] = z;
    }
    const bool diag = (kb == qb);
#pragma unroll
    for (int nt = 0; nt < 4; ++nt)
#pragma unroll
      for (int r = 0; r < 4; ++r) {
        float v = s[nt][r] * 0.125f;   // 1/sqrt(64)
        if (diag) {
          int colg = kb * 64 + nt * 16 + l15;
          int rowg = qb * 64 + wave * 16 + quad * 4 + r;
          if (colg > rowg) v = -1e30f;
        }
        s[nt][r] = v;
      }

    // ---- online softmax (rows = quad*4+r, reduce across 16 col-lanes) ----
    float tmax[4];
#pragma unroll
    for (int r = 0; r < 4; ++r)
      tmax[r] = fmaxf(fmaxf(s[0][r], s[1][r]), fmaxf(s[2][r], s[3][r]));
#pragma unroll
    for (int mk = 1; mk <= 8; mk <<= 1)
#pragma unroll
      for (int r = 0; r < 4; ++r)
        tmax[r] = fmaxf(tmax[r], __shfl_xor(tmax[r], mk));

    float alpha[4];
#pragma unroll
    for (int r = 0; r < 4; ++r) {
      float mn = fmaxf(m_r[r], tmax[r]);
      alpha[r] = __expf(m_r[r] - mn);
      m_r[r] = mn;
    }

    float psum[4] = {0.f, 0.f, 0.f, 0.f};
#pragma unroll
    for (int nt = 0; nt < 4; ++nt)
#pragma unroll
      for (int r = 0; r < 4; ++r) {
        float p = __expf(s[nt][r] - m_r[r]);
        psum[r] += p;
        Plds[wave][quad * 4 + r][nt * 16 + l15] = __float2bfloat16(p);
      }
#pragma unroll
    for (int mk = 1; mk <= 8; mk <<= 1)
#pragma unroll
      for (int r = 0; r < 4; ++r) psum[r] += __shfl_xor(psum[r], mk);
#pragma unroll
    for (int r = 0; r < 4; ++r) l_r[r] = alpha[r] * l_r[r] + psum[r];

    __syncthreads();  // P visible (per-wave, but keep uniform barrier: safe)

    // ---- O = alpha*O + P V ----
#pragma unroll
    for (int dt = 0; dt < 4; ++dt)
#pragma unroll
      for (int r = 0; r < 4; ++r) o[dt][r] *= alpha[r];

    short8 p0 = *(const short8*)(&Plds[wave][l15][quad * 8]);
    short8 p1 = *(const short8*)(&Plds[wave][l15][32 + quad * 8]);
#pragma unroll
    for (int dt = 0; dt < 4; ++dt) {
      short8 v0 = *(const short8*)(&Vlds[dt * 16 + l15][quad * 8]);
      short8 v1 = *(const short8*)(&Vlds[dt * 16 + l15][32 + quad * 8]);
      o[dt] = __builtin_amdgcn_mfma_f32_16x16x32_bf16(p0, v0, o[dt], 0, 0, 0);
      o[dt] = __builtin_amdgcn_mfma_f32_16x16x32_bf16(p1, v1, o[dt], 0, 0, 0);
    }
    __syncthreads();  // before next iter overwrites Klds/Vlds
  }

  // ---- epilogue: ctx = O / l ----
#pragma unroll
  for (int dt = 0; dt < 4; ++dt)
#pragma unroll
    for (int r = 0; r < 4; ++r) {
      int rowg = qb * 64 + wave * 16 + quad * 4 + r;
      ctx[((size_t)b * S_ + rowg) * D_ + h * HD_ + dt * 16 + l15] =
          __float2bfloat16(o[dt][r] / l_r[r]);
    }
}

// --------------------------------------------------------------- launch ----
extern "C" void kernel_launch(void* const* d_in, const int* in_sizes, int n_in,
                              void* d_out, int out_size, void* d_ws,
                              size_t ws_size, hipStream_t stream) {
  const float* x      = (const float*)d_in[0];
  const float* w_qkv  = (const float*)d_in[1];
  const float* b_qkv  = (const float*)d_in[2];
  const float* w_proj = (const float*)d_in[3];
  const float* b_proj = (const float*)d_in[4];
  float* out = (float*)d_out;

  char* ws = (char*)d_ws;
  __hip_bfloat16* xb     = (__hip_bfloat16*)(ws + 0);          // 16 MB
  __hip_bfloat16* wqkvT  = (__hip_bfloat16*)(ws + 16777216);   // 6 MB [3072][1024]
  __hip_bfloat16* wprojT = (__hip_bfloat16*)(ws + 23068672);   // 2 MB [1024][1024]
  __hip_bfloat16* qkvb   = (__hip_bfloat16*)(ws + 25165824);   // 50.3 MB
  __hip_bfloat16* ctx    = (__hip_bfloat16*)(ws + 75497472);   // 16 MB

  cast_f32_bf16<<<8192, 256, 0, stream>>>(x, xb, M_ * D_);
  transpose_cast<<<dim3(N3_ / 32, D_ / 32), dim3(32, 8), 0, stream>>>(
      w_qkv, wqkvT, D_, N3_);
  transpose_cast<<<dim3(D_ / 32, D_ / 32), dim3(32, 8), 0, stream>>>(
      w_proj, wprojT, D_, D_);

  gemm_bt_bias<__hip_bfloat16><<<dim3(N3_ / 128, M_ / 128), 256, 0, stream>>>(
      xb, wqkvT, b_qkv, qkvb, M_, N3_, D_);

  attn_causal<<<dim3(S_ / 64, H_, B_), 256, 0, stream>>>(qkvb, ctx);

  gemm_bt_bias<float><<<dim3(D_ / 128, M_ / 128), 256, 0, stream>>>(
      ctx, wprojT, b_proj, out, M_, D_, D_);
}

// Round 2
// 342.825 us; speedup vs baseline: 1.5396x; 1.5396x over previous
//
#include <hip/hip_runtime.h>
#include <hip/hip_bf16.h>

typedef __attribute__((ext_vector_type(8))) short short8;
typedef __attribute__((ext_vector_type(4))) float f32x4;

#define B_   4
#define S_   2048
#define D_   1024
#define H_   16
#define HD_  64
#define M_   (B_ * S_)      // 8192
#define N3_  (3 * D_)       // 3072
#define NQB  (S_ / 64)      // 32

// ---------------------------------------------------------------- casts ----
__global__ __launch_bounds__(256) void cast_f32_bf16(
    const float* __restrict__ in, __hip_bfloat16* __restrict__ out, int n) {
  int i = (blockIdx.x * 256 + threadIdx.x) * 4;
  if (i + 3 < n) {
    float4 v = *(const float4*)(in + i);
    union { ushort4 u4; __hip_bfloat16 h[4]; } p;
    p.h[0] = __float2bfloat16(v.x);
    p.h[1] = __float2bfloat16(v.y);
    p.h[2] = __float2bfloat16(v.z);
    p.h[3] = __float2bfloat16(v.w);
    *(ushort4*)(out + i) = p.u4;
  }
}

// in: [rows][cols] fp32 -> out: [cols][rows] bf16
__global__ __launch_bounds__(256) void transpose_cast(
    const float* __restrict__ in, __hip_bfloat16* __restrict__ out,
    int rows, int cols) {
  __shared__ float tile[32][33];
  int bx = blockIdx.x * 32;  // col base
  int by = blockIdx.y * 32;  // row base
  int tx = threadIdx.x, ty = threadIdx.y;   // (32, 8)
#pragma unroll
  for (int i = 0; i < 4; ++i)
    tile[ty + i * 8][tx] = in[(size_t)(by + ty + i * 8) * cols + bx + tx];
  __syncthreads();
#pragma unroll
  for (int i = 0; i < 4; ++i)
    out[(size_t)(bx + ty + i * 8) * rows + by + tx] =
        __float2bfloat16(tile[tx][ty + i * 8]);
}

// V slice of qkv -> Vt[(b*H+h)][d][S]  (bf16 -> bf16 transpose per head)
__global__ __launch_bounds__(256) void transpose_v(
    const __hip_bfloat16* __restrict__ qkv, __hip_bfloat16* __restrict__ vt) {
  __shared__ __hip_bfloat16 tile[32][33];
  const int sb = blockIdx.x * 32;           // seq base
  const int db = blockIdx.y * 32;           // head-dim base (0 or 32)
  const int bh = blockIdx.z;                // b*16 + h
  const int b = bh >> 4, hh = bh & 15;
  const int tx = threadIdx.x, ty = threadIdx.y;   // (32, 8)
  const size_t src = (size_t)b * S_ * N3_ + 2 * D_ + hh * HD_;
#pragma unroll
  for (int i = 0; i < 4; ++i)
    tile[ty + i * 8][tx] =
        qkv[src + (size_t)(sb + ty + i * 8) * N3_ + db + tx];
  __syncthreads();
  const size_t dst = (size_t)bh * HD_ * S_;
#pragma unroll
  for (int i = 0; i < 4; ++i)
    vt[dst + (size_t)(db + ty + i * 8) * S_ + sb + tx] = tile[tx][ty + i * 8];
}

// ----------------------------------------------------------------- GEMM ----
// C[M][N] = A[M][K] * Bt[N][K]^T + bias[N].  128x128 tile, BK=32, 256 thr.
__device__ inline void store_out(float* p, float v) { *p = v; }
__device__ inline void store_out(__hip_bfloat16* p, float v) {
  *p = __float2bfloat16(v);
}

template <typename OUT_T>
__global__ __launch_bounds__(256) void gemm_bt_bias(
    const __hip_bfloat16* __restrict__ A, const __hip_bfloat16* __restrict__ Bt,
    const float* __restrict__ bias, OUT_T* __restrict__ C,
    int M, int N, int K) {
  __shared__ __hip_bfloat16 Alds[128][40];
  __shared__ __hip_bfloat16 Blds[128][40];
  const int t = threadIdx.x;
  const int wave = t >> 6, lane = t & 63;
  const int quad = lane >> 4, l15 = lane & 15;
  const int wm = (wave >> 1) * 64, wn = (wave & 1) * 64;
  const int m0 = blockIdx.y * 128, n0 = blockIdx.x * 128;

  f32x4 acc[4][4] = {};

  for (int k0 = 0; k0 < K; k0 += 32) {
#pragma unroll
    for (int i = 0; i < 2; ++i) {
      int c = t + 256 * i;
      int row = c >> 2, seg = c & 3;
      *(uint4*)(&Alds[row][seg * 8]) =
          *(const uint4*)(A + (size_t)(m0 + row) * K + k0 + seg * 8);
      *(uint4*)(&Blds[row][seg * 8]) =
          *(const uint4*)(Bt + (size_t)(n0 + row) * K + k0 + seg * 8);
    }
    __syncthreads();
    short8 a[4], b[4];
#pragma unroll
    for (int mt = 0; mt < 4; ++mt)
      a[mt] = *(const short8*)(&Alds[wm + mt * 16 + l15][quad * 8]);
#pragma unroll
    for (int nt = 0; nt < 4; ++nt)
      b[nt] = *(const short8*)(&Blds[wn + nt * 16 + l15][quad * 8]);
#pragma unroll
    for (int mt = 0; mt < 4; ++mt)
#pragma unroll
      for (int nt = 0; nt < 4; ++nt)
        acc[mt][nt] = __builtin_amdgcn_mfma_f32_16x16x32_bf16(
            a[mt], b[nt], acc[mt][nt], 0, 0, 0);
    __syncthreads();
  }

#pragma unroll
  for (int mt = 0; mt < 4; ++mt)
#pragma unroll
    for (int nt = 0; nt < 4; ++nt) {
      int col = n0 + wn + nt * 16 + l15;
      float bv = bias[col];
#pragma unroll
      for (int r = 0; r < 4; ++r) {
        int row = m0 + wm + mt * 16 + quad * 4 + r;
        store_out(C + (size_t)row * N + col, acc[mt][nt][r] + bv);
      }
    }
}

// ------------------------------------------------------ flash attention ----
// qkv: [B*S][3072] bf16 (Q,K slices), vt: [(b*H+h)][64][S] bf16 (V^T).
// Block x in 0..15 handles qb = x and qb = 31-x  -> uniform 33 kb-iters.
__global__ __launch_bounds__(256) void attn_causal(
    const __hip_bfloat16* __restrict__ qkv,
    const __hip_bfloat16* __restrict__ vt,
    __hip_bfloat16* __restrict__ ctx) {
  __shared__ __hip_bfloat16 Klds[64][72];      // [kpos][d]
  __shared__ __hip_bfloat16 Vlds[64][72];      // [d][kpos]  (from Vt, vector)
  __shared__ __hip_bfloat16 Plds[4][16][72];   // per-wave P round-trip

  const int t = threadIdx.x;
  const int wave = t >> 6, lane = t & 63;
  const int quad = lane >> 4, l15 = lane & 15;
  const int xb = blockIdx.x, h = blockIdx.y, b = blockIdx.z;

  const size_t qbase = (size_t)b * S_ * N3_ + h * HD_;
  const size_t kbase = qbase + D_;
  const size_t vtbase = (size_t)(b * H_ + h) * HD_ * S_;
  const float C2 = 0.18033688f;  // (1/sqrt(64)) * log2(e)

  for (int sel = 0; sel < 2; ++sel) {
    const int qb = sel ? (NQB - 1 - xb) : xb;
    const int qrow = qb * 64 + wave * 16 + l15;
    short8 qf0 = *(const short8*)(qkv + qbase + (size_t)qrow * N3_ + quad * 8);
    short8 qf1 =
        *(const short8*)(qkv + qbase + (size_t)qrow * N3_ + 32 + quad * 8);

    f32x4 o[4] = {};
    float m_r[4], l_r[4];
#pragma unroll
    for (int r = 0; r < 4; ++r) { m_r[r] = -1e30f; l_r[r] = 0.f; }

    for (int kb = 0; kb <= qb; ++kb) {
      // ---- stage K [kpos][d] and V^T [d][kpos], both vectorized ----
#pragma unroll
      for (int i = 0; i < 2; ++i) {
        int c = t + 256 * i;
        int row = c >> 3, seg = c & 7;
        *(uint4*)(&Klds[row][seg * 8]) = *(const uint4*)(
            qkv + kbase + (size_t)(kb * 64 + row) * N3_ + seg * 8);
        *(uint4*)(&Vlds[row][seg * 8]) = *(const uint4*)(
            vt + vtbase + (size_t)row * S_ + kb * 64 + seg * 8);
      }
      __syncthreads();

      // ---- scores in log2 domain: s = (Q K^T) * C2 ----
      f32x4 s[4];
#pragma unroll
      for (int nt = 0; nt < 4; ++nt) {
        f32x4 z = {};
        short8 k0 = *(const short8*)(&Klds[nt * 16 + l15][quad * 8]);
        short8 k1 = *(const short8*)(&Klds[nt * 16 + l15][32 + quad * 8]);
        z = __builtin_amdgcn_mfma_f32_16x16x32_bf16(qf0, k0, z, 0, 0, 0);
        z = __builtin_amdgcn_mfma_f32_16x16x32_bf16(qf1, k1, z, 0, 0, 0);
        s[nt] = z;
      }
      const bool diag = (kb == qb);
#pragma unroll
      for (int nt = 0; nt < 4; ++nt)
#pragma unroll
        for (int r = 0; r < 4; ++r) {
          float v = s[nt][r] * C2;
          if (diag) {
            int colg = nt * 16 + l15;
            int rowg = wave * 16 + quad * 4 + r;
            if (colg > rowg) v = -1e30f;
          }
          s[nt][r] = v;
        }

      // ---- online softmax (rows = quad*4+r, reduce across 16 col-lanes) ----
      float tmax[4];
#pragma unroll
      for (int r = 0; r < 4; ++r)
        tmax[r] = fmaxf(fmaxf(s[0][r], s[1][r]), fmaxf(s[2][r], s[3][r]));
#pragma unroll
      for (int mk = 1; mk <= 8; mk <<= 1)
#pragma unroll
        for (int r = 0; r < 4; ++r)
          tmax[r] = fmaxf(tmax[r], __shfl_xor(tmax[r], mk));

      float alpha[4];
#pragma unroll
      for (int r = 0; r < 4; ++r) {
        float mn = fmaxf(m_r[r], tmax[r]);
        alpha[r] = __builtin_amdgcn_exp2f(m_r[r] - mn);
        m_r[r] = mn;
      }

      float psum[4] = {0.f, 0.f, 0.f, 0.f};
#pragma unroll
      for (int nt = 0; nt < 4; ++nt)
#pragma unroll
        for (int r = 0; r < 4; ++r) {
          float p = __builtin_amdgcn_exp2f(s[nt][r] - m_r[r]);
          psum[r] += p;
          Plds[wave][quad * 4 + r][nt * 16 + l15] = __float2bfloat16(p);
        }
#pragma unroll
      for (int mk = 1; mk <= 8; mk <<= 1)
#pragma unroll
        for (int r = 0; r < 4; ++r) psum[r] += __shfl_xor(psum[r], mk);
#pragma unroll
      for (int r = 0; r < 4; ++r) l_r[r] = alpha[r] * l_r[r] + psum[r];

      __syncthreads();

      // ---- O = alpha*O + P V ----
#pragma unroll
      for (int dt = 0; dt < 4; ++dt)
#pragma unroll
        for (int r = 0; r < 4; ++r) o[dt][r] *= alpha[r];

      short8 p0 = *(const short8*)(&Plds[wave][l15][quad * 8]);
      short8 p1 = *(const short8*)(&Plds[wave][l15][32 + quad * 8]);
#pragma unroll
      for (int dt = 0; dt < 4; ++dt) {
        short8 v0 = *(const short8*)(&Vlds[dt * 16 + l15][quad * 8]);
        short8 v1 = *(const short8*)(&Vlds[dt * 16 + l15][32 + quad * 8]);
        o[dt] = __builtin_amdgcn_mfma_f32_16x16x32_bf16(p0, v0, o[dt], 0, 0, 0);
        o[dt] = __builtin_amdgcn_mfma_f32_16x16x32_bf16(p1, v1, o[dt], 0, 0, 0);
      }
      __syncthreads();  // before next iter/tile overwrites Klds/Vlds
    }

    // ---- epilogue: ctx = O / l ----
#pragma unroll
    for (int dt = 0; dt < 4; ++dt)
#pragma unroll
      for (int r = 0; r < 4; ++r) {
        int rowg = qb * 64 + wave * 16 + quad * 4 + r;
        ctx[((size_t)b * S_ + rowg) * D_ + h * HD_ + dt * 16 + l15] =
            __float2bfloat16(o[dt][r] / l_r[r]);
      }
  }
}

// --------------------------------------------------------------- launch ----
extern "C" void kernel_launch(void* const* d_in, const int* in_sizes, int n_in,
                              void* d_out, int out_size, void* d_ws,
                              size_t ws_size, hipStream_t stream) {
  const float* x      = (const float*)d_in[0];
  const float* w_qkv  = (const float*)d_in[1];
  const float* b_qkv  = (const float*)d_in[2];
  const float* w_proj = (const float*)d_in[3];
  const float* b_proj = (const float*)d_in[4];
  float* out = (float*)d_out;

  char* ws = (char*)d_ws;
  __hip_bfloat16* xb     = (__hip_bfloat16*)(ws + 0);          // 16 MB (dead after GEMM1)
  __hip_bfloat16* vtb    = (__hip_bfloat16*)(ws + 0);          // 16 MB, reuses xb
  __hip_bfloat16* wqkvT  = (__hip_bfloat16*)(ws + 16777216);   // 6 MB [3072][1024]
  __hip_bfloat16* wprojT = (__hip_bfloat16*)(ws + 23068672);   // 2 MB [1024][1024]
  __hip_bfloat16* qkvb   = (__hip_bfloat16*)(ws + 25165824);   // 50.3 MB
  __hip_bfloat16* ctx    = (__hip_bfloat16*)(ws + 75497472);   // 16 MB

  cast_f32_bf16<<<8192, 256, 0, stream>>>(x, xb, M_ * D_);
  transpose_cast<<<dim3(N3_ / 32, D_ / 32), dim3(32, 8), 0, stream>>>(
      w_qkv, wqkvT, D_, N3_);
  transpose_cast<<<dim3(D_ / 32, D_ / 32), dim3(32, 8), 0, stream>>>(
      w_proj, wprojT, D_, D_);

  gemm_bt_bias<__hip_bfloat16><<<dim3(N3_ / 128, M_ / 128), 256, 0, stream>>>(
      xb, wqkvT, b_qkv, qkvb, M_, N3_, D_);

  transpose_v<<<dim3(S_ / 32, HD_ / 32, B_ * H_), dim3(32, 8), 0, stream>>>(
      qkvb, vtb);

  attn_causal<<<dim3(NQB / 2, H_, B_), 256, 0, stream>>>(qkvb, vtb, ctx);

  gemm_bt_bias<float><<<dim3(D_ / 128, M_ / 128), 256, 0, stream>>>(
      ctx, wprojT, b_proj, out, M_, D_, D_);
}